// Round 1
// baseline (833.749 us; speedup 1.0000x reference)
//
#include <hip/hip_runtime.h>
#include <math.h>

// Problem constants
#define NH    8
#define NL    3
#define NPT   4
#define HD    32
#define DIM   256
#define NQ    8400
#define BATCH 4
#define STOT  8400   // 6400 + 1600 + 400

// GEMM tiling
#define BM 64
#define BN 64
#define BK 16

// C[M,N] = A[M,K] @ W[K,N] + bias ; A row-major.
__global__ __launch_bounds__(256) void gemm_rm(
    const float* __restrict__ A, const float* __restrict__ W,
    const float* __restrict__ bias, float* __restrict__ C,
    int M, int N, int K)
{
    __shared__ float As[BK][BM + 1];
    __shared__ float Ws[BK][BN + 1];
    const int tid = threadIdx.x;
    const int bm = blockIdx.y * BM;
    const int bn = blockIdx.x * BN;
    const int tx = tid & 15, ty = tid >> 4;
    float acc[4][4] = {};

    for (int k0 = 0; k0 < K; k0 += BK) {
        // A tile: 64 rows x 16 k. 16 consecutive lanes read 16 contiguous k (64B segs).
        #pragma unroll
        for (int i = 0; i < 4; ++i) {
            int r  = i * 16 + (tid >> 4);
            int kk = tid & 15;
            int gm = bm + r;
            float v = 0.f;
            if (gm < M) v = A[(size_t)gm * K + k0 + kk];
            As[kk][r] = v;
        }
        // W tile: 16 k x 64 n. 64 consecutive lanes read 256B rows.
        #pragma unroll
        for (int i = 0; i < 4; ++i) {
            int kk = i * 4 + (tid >> 6);
            int nn = tid & 63;
            int gn = bn + nn;
            float v = 0.f;
            if (gn < N) v = W[(size_t)(k0 + kk) * N + gn];
            Ws[kk][nn] = v;
        }
        __syncthreads();
        #pragma unroll
        for (int kk = 0; kk < BK; ++kk) {
            float a[4], bv[4];
            #pragma unroll
            for (int r = 0; r < 4; ++r) a[r] = As[kk][ty * 4 + r];
            #pragma unroll
            for (int c = 0; c < 4; ++c) bv[c] = Ws[kk][tx * 4 + c];
            #pragma unroll
            for (int r = 0; r < 4; ++r)
                #pragma unroll
                for (int c = 0; c < 4; ++c)
                    acc[r][c] += a[r] * bv[c];
        }
        __syncthreads();
    }
    #pragma unroll
    for (int r = 0; r < 4; ++r) {
        int gm = bm + ty * 4 + r;
        if (gm >= M) continue;
        #pragma unroll
        for (int c = 0; c < 4; ++c) {
            int gn = bn + tx * 4 + c;
            if (gn < N) C[(size_t)gm * N + gn] = acc[r][c] + bias[gn];
        }
    }
}

// Value projection for one level:
// val[b, base+s, n] = sum_k feat[b, k, s] * W[k, n] + bias[n]
// feat is [B, D, S] (A^T access: contiguous in s == m).
__global__ __launch_bounds__(256) void gemm_feat(
    const float* __restrict__ feat, const float* __restrict__ W,
    const float* __restrict__ bias, float* __restrict__ val,
    int S, int base)
{
    __shared__ float As[BK][BM + 1];
    __shared__ float Ws[BK][BN + 1];
    const int tid = threadIdx.x;
    const int b  = blockIdx.z;
    const int bm = blockIdx.y * BM;   // s tile
    const int bn = blockIdx.x * BN;   // n tile
    const int tx = tid & 15, ty = tid >> 4;
    const float* fb = feat + (size_t)b * DIM * S;
    float acc[4][4] = {};

    for (int k0 = 0; k0 < DIM; k0 += BK) {
        #pragma unroll
        for (int i = 0; i < 4; ++i) {
            int kk = i * 4 + (tid >> 6);
            int mm = tid & 63;
            int gs = bm + mm;
            float v = 0.f;
            if (gs < S) v = fb[(size_t)(k0 + kk) * S + gs];
            As[kk][mm] = v;
        }
        #pragma unroll
        for (int i = 0; i < 4; ++i) {
            int kk = i * 4 + (tid >> 6);
            int nn = tid & 63;
            Ws[kk][nn] = W[(size_t)(k0 + kk) * DIM + bn + nn];
        }
        __syncthreads();
        #pragma unroll
        for (int kk = 0; kk < BK; ++kk) {
            float a[4], bv[4];
            #pragma unroll
            for (int r = 0; r < 4; ++r) a[r] = As[kk][ty * 4 + r];
            #pragma unroll
            for (int c = 0; c < 4; ++c) bv[c] = Ws[kk][tx * 4 + c];
            #pragma unroll
            for (int r = 0; r < 4; ++r)
                #pragma unroll
                for (int c = 0; c < 4; ++c)
                    acc[r][c] += a[r] * bv[c];
        }
        __syncthreads();
    }
    #pragma unroll
    for (int r = 0; r < 4; ++r) {
        int gs = bm + ty * 4 + r;
        if (gs >= S) continue;
        #pragma unroll
        for (int c = 0; c < 4; ++c) {
            int gn = bn + tx * 4 + c;
            val[((size_t)b * STOT + base + gs) * DIM + gn] = acc[r][c] + bias[gn];
        }
    }
}

// One block per (b,q): softmax + tanh-offset setup in LDS, then gather-accumulate.
__global__ __launch_bounds__(256) void sample_kernel(
    const float* __restrict__ val,       // [B, STOT, DIM]
    const float* __restrict__ raw_off,   // [B*Q, 192]
    const float* __restrict__ raw_attn,  // [B*Q, 96]
    const float* __restrict__ refp,      // [B, Q, 2]
    float* __restrict__ out_tmp)         // [B*Q, DIM]
{
    const int bq = blockIdx.x;
    const int b  = bq / NQ;
    const int t  = threadIdx.x;

    __shared__ float s_w[NH * 12][4];
    __shared__ int   s_idx[NH * 12][4];
    __shared__ float s_aw[NH][12];
    __shared__ float s_raw[NH][12];

    if (t < 96) s_raw[t / 12][t % 12] = raw_attn[(size_t)bq * 96 + t];
    __syncthreads();

    if (t < NH) {
        float m = -1e30f;
        #pragma unroll
        for (int j = 0; j < 12; ++j) m = fmaxf(m, s_raw[t][j]);
        float s = 0.f, e[12];
        #pragma unroll
        for (int j = 0; j < 12; ++j) { e[j] = expf(s_raw[t][j] - m); s += e[j]; }
        float inv = 1.f / s;
        #pragma unroll
        for (int j = 0; j < 12; ++j) s_aw[t][j] = e[j] * inv;
    }
    __syncthreads();

    if (t < 96) {
        const int h = t / 12, lp = t % 12, l = lp >> 2;
        const int dims[3]  = {80, 40, 20};
        const int bases[3] = {0, 6400, 8000};
        const int Wl = dims[l], Hl = dims[l];
        float rawx = raw_off[(size_t)bq * 192 + h * 24 + lp * 2 + 0];
        float rawy = raw_off[(size_t)bq * 192 + h * 24 + lp * 2 + 1];
        float rx = refp[(size_t)bq * 2 + 0];
        float ry = refp[(size_t)bq * 2 + 1];
        // grid in [-1,1], then unnormalize (align_corners=False)
        float gx = (rx + tanhf(rawx) * 0.5f) * 2.f - 1.f;
        float gy = (ry + tanhf(rawy) * 0.5f) * 2.f - 1.f;
        float ix = ((gx + 1.f) * Wl - 1.f) * 0.5f;
        float iy = ((gy + 1.f) * Hl - 1.f) * 0.5f;
        float x0f = floorf(ix), y0f = floorf(iy);
        float fx = ix - x0f, fy = iy - y0f;
        int x0 = (int)x0f, y0 = (int)y0f;
        int x1 = x0 + 1,   y1 = y0 + 1;
        float aw = s_aw[h][lp];
        float w00 = (1.f - fx) * (1.f - fy) * aw;
        float w01 = fx * (1.f - fy) * aw;
        float w10 = (1.f - fx) * fy * aw;
        float w11 = fx * fy * aw;
        bool vx0 = (x0 >= 0) && (x0 < Wl);
        bool vx1 = (x1 >= 0) && (x1 < Wl);
        bool vy0 = (y0 >= 0) && (y0 < Hl);
        bool vy1 = (y1 >= 0) && (y1 < Hl);
        int base = bases[l];
        s_idx[t][0] = (vx0 && vy0) ? base + y0 * Wl + x0 : -1;  s_w[t][0] = w00;
        s_idx[t][1] = (vx1 && vy0) ? base + y0 * Wl + x1 : -1;  s_w[t][1] = w01;
        s_idx[t][2] = (vx0 && vy1) ? base + y1 * Wl + x0 : -1;  s_w[t][2] = w10;
        s_idx[t][3] = (vx1 && vy1) ? base + y1 * Wl + x1 : -1;  s_w[t][3] = w11;
    }
    __syncthreads();

    const int h = t >> 5, c = t & 31;
    const float* vb = val + ((size_t)b * STOT) * DIM + h * HD + c;
    float acc = 0.f;
    #pragma unroll
    for (int j = 0; j < 12; ++j) {
        int pt = h * 12 + j;
        #pragma unroll
        for (int k = 0; k < 4; ++k) {
            int idx = s_idx[pt][k];
            if (idx >= 0) acc += s_w[pt][k] * vb[(size_t)idx * DIM];
        }
    }
    out_tmp[(size_t)bq * DIM + t] = acc;
}

extern "C" void kernel_launch(void* const* d_in, const int* in_sizes, int n_in,
                              void* d_out, int out_size, void* d_ws, size_t ws_size,
                              hipStream_t stream)
{
    const float* query  = (const float*)d_in[0];
    const float* feat0  = (const float*)d_in[1];
    const float* feat1  = (const float*)d_in[2];
    const float* feat2  = (const float*)d_in[3];
    const float* refp   = (const float*)d_in[4];
    const float* W_off  = (const float*)d_in[5];
    const float* b_off  = (const float*)d_in[6];
    const float* W_attn = (const float*)d_in[7];
    const float* b_attn = (const float*)d_in[8];
    const float* W_val  = (const float*)d_in[9];
    const float* b_val  = (const float*)d_in[10];
    const float* W_out  = (const float*)d_in[11];
    const float* b_out  = (const float*)d_in[12];
    float* out = (float*)d_out;

    // workspace layout (floats): 107.5 MB total
    float* val      = (float*)d_ws;                        // B*STOT*DIM   = 8,601,600
    float* raw_off  = val      + (size_t)BATCH * STOT * DIM;
    float* raw_attn = raw_off  + (size_t)BATCH * NQ * 192; // 6,451,200
    float* out_tmp  = raw_attn + (size_t)BATCH * NQ * 96;  // 3,225,600

    dim3 blk(256);
    const int MQ = BATCH * NQ;  // 33600, = 525 * 64

    // value projection, per level (fused with layout transform to [B,S,DIM])
    gemm_feat<<<dim3(4, (6400 + 63) / 64, BATCH), blk, 0, stream>>>(feat0, W_val, b_val, val, 6400, 0);
    gemm_feat<<<dim3(4, (1600 + 63) / 64, BATCH), blk, 0, stream>>>(feat1, W_val, b_val, val, 1600, 6400);
    gemm_feat<<<dim3(4, (400  + 63) / 64, BATCH), blk, 0, stream>>>(feat2, W_val, b_val, val, 400, 8000);

    // raw sampling offsets and attention logits
    gemm_rm<<<dim3(3, 525), blk, 0, stream>>>(query, W_off,  b_off,  raw_off,  MQ, 192, 256);
    gemm_rm<<<dim3(2, 525), blk, 0, stream>>>(query, W_attn, b_attn, raw_attn, MQ,  96, 256);

    // deformable sampling + head-weighted sum
    sample_kernel<<<dim3(MQ), blk, 0, stream>>>(val, raw_off, raw_attn, refp, out_tmp);

    // output projection
    gemm_rm<<<dim3(4, 525), blk, 0, stream>>>(out_tmp, W_out, b_out, out, MQ, 256, 256);
}

// Round 2
// 317.695 us; speedup vs baseline: 2.6244x; 2.6244x over previous
//
#include <hip/hip_runtime.h>
#include <math.h>

#define NH    8
#define NPT   4
#define DIM   256
#define NQ    8400
#define BATCH 4
#define STOT  8400
#define MQ    (BATCH * NQ)   // 33600

typedef __attribute__((ext_vector_type(8))) short  s16x8;
typedef __attribute__((ext_vector_type(8))) unsigned short u16x8;
typedef __attribute__((ext_vector_type(4))) float  f32x4;

static __device__ __forceinline__ unsigned short f2bf(float x) {
    union { float f; unsigned u; } v; v.f = x;
    unsigned r = v.u + 0x7fffu + ((v.u >> 16) & 1u);   // RNE
    return (unsigned short)(r >> 16);
}
static __device__ __forceinline__ float bf2f(unsigned short h) {
    union { float f; unsigned u; } v; v.u = ((unsigned)h) << 16;
    return v.f;
}

// ---------------------------------------------------------------------------
// Transpose-convert a weight matrix W[K][Nw] (fp32) -> outH[(n0+n)*256 + k]
// (bf16), optional lo plane for bf16x2 split. K assumed 256.
__global__ __launch_bounds__(256) void tp_w(
    const float* __restrict__ W, int Nw,
    unsigned short* __restrict__ outH, unsigned short* __restrict__ outL, int n0)
{
    __shared__ float tile[32][33];
    const int t = threadIdx.x;
    const int nb = blockIdx.x * 32, k0 = blockIdx.y * 32;
    const int c = t & 31, r = t >> 5;   // r in 0..7
    #pragma unroll
    for (int i = 0; i < 4; ++i) {
        int k = k0 + r + i * 8, n = nb + c;
        tile[r + i * 8][c] = (n < Nw) ? W[(size_t)k * Nw + n] : 0.f;
    }
    __syncthreads();
    #pragma unroll
    for (int i = 0; i < 4; ++i) {
        int n = nb + r + i * 8, k = k0 + c;
        if (n < Nw) {
            float x = tile[c][r + i * 8];
            unsigned short h = f2bf(x);
            outH[(size_t)(n0 + n) * 256 + k] = h;
            if (outL) outL[(size_t)(n0 + n) * 256 + k] = f2bf(x - bf2f(h));
        }
    }
}

// feat [B][256][S] fp32 -> Abf[(b*STOT + base + s)*256 + k] bf16
__global__ __launch_bounds__(256) void tp_feat(
    const float* __restrict__ feat, int S, int base,
    unsigned short* __restrict__ Abf)
{
    __shared__ float tile[32][33];
    const int t = threadIdx.x;
    const int s0 = blockIdx.x * 32, k0 = blockIdx.y * 32, b = blockIdx.z;
    const int c = t & 31, r = t >> 5;
    #pragma unroll
    for (int i = 0; i < 4; ++i) {
        int k = k0 + r + i * 8, s = s0 + c;
        tile[r + i * 8][c] = (s < S) ? feat[((size_t)b * 256 + k) * S + s] : 0.f;
    }
    __syncthreads();
    #pragma unroll
    for (int i = 0; i < 4; ++i) {
        int s = s0 + r + i * 8, k = k0 + c;
        if (s < S)
            Abf[((size_t)(b * STOT + base + s)) * 256 + k] = f2bf(tile[c][r + i * 8]);
    }
}

__global__ void cat_bias(const float* __restrict__ boff, const float* __restrict__ battn,
                         float* __restrict__ bcat)
{
    int t = blockIdx.x * 256 + threadIdx.x;
    if (t < 192) bcat[t] = boff[t];
    else if (t < 288) bcat[t] = battn[t - 192];
}

// ---------------------------------------------------------------------------
// C[M][N] = A[M][K] * B^T (Bt is [N][K] bf16) + bias.
// SPLIT: A is fp32, converted hi/lo in staging; B has hi+lo planes; 3 MFMA
// passes per tile pair (bf16x2 precision). !SPLIT: A is bf16 [M][K].
// Tile 128x128, BK=32, 4 waves each computing 64x64 via 16x16x32 MFMA.
template<bool SPLIT>
__global__ __launch_bounds__(256) void gemm_bt(
    const void* __restrict__ Aptr,
    const unsigned short* __restrict__ Bh, const unsigned short* __restrict__ Bl,
    const float* __restrict__ bias, float* __restrict__ C,
    int M, int N, int K)
{
    __shared__ unsigned short Ah[128 * 40];
    __shared__ unsigned short Bs[128 * 40];
    __shared__ unsigned short Al[SPLIT ? 128 * 40 : 8];
    __shared__ unsigned short Blo[SPLIT ? 128 * 40 : 8];

    const int t = threadIdx.x;
    const int bn = blockIdx.x * 128, bm = blockIdx.y * 128;
    const int lane = t & 63, w = t >> 6;
    const int wm = (w & 1) * 64, wn = (w >> 1) * 64;
    const int l15 = lane & 15, quad = lane >> 4;

    f32x4 acc[4][4];
    #pragma unroll
    for (int i = 0; i < 4; ++i)
        #pragma unroll
        for (int j = 0; j < 4; ++j)
            acc[i][j] = (f32x4){0.f, 0.f, 0.f, 0.f};

    for (int k0 = 0; k0 < K; k0 += 32) {
        // ---- stage A ----
        #pragma unroll
        for (int cc = 0; cc < 2; ++cc) {
            int cid = t + cc * 256;           // 0..511
            int r = cid >> 2, s = cid & 3;
            int gr = bm + r; if (gr > M - 1) gr = M - 1;
            if constexpr (SPLIT) {
                const float* ap = (const float*)Aptr + (size_t)gr * K + k0 + s * 8;
                float4 f0 = *(const float4*)ap;
                float4 f1 = *(const float4*)(ap + 4);
                float xs[8] = {f0.x, f0.y, f0.z, f0.w, f1.x, f1.y, f1.z, f1.w};
                u16x8 hv, lv;
                #pragma unroll
                for (int e = 0; e < 8; ++e) {
                    unsigned short h = f2bf(xs[e]);
                    hv[e] = h;
                    lv[e] = f2bf(xs[e] - bf2f(h));
                }
                *(u16x8*)&Ah[r * 40 + s * 8] = hv;
                *(u16x8*)&Al[r * 40 + s * 8] = lv;
            } else {
                u16x8 v = *(const u16x8*)((const unsigned short*)Aptr + (size_t)gr * K + k0 + s * 8);
                *(u16x8*)&Ah[r * 40 + s * 8] = v;
            }
        }
        // ---- stage B ----
        #pragma unroll
        for (int cc = 0; cc < 2; ++cc) {
            int cid = t + cc * 256;
            int r = cid >> 2, s = cid & 3;
            int gn = bn + r; if (gn > N - 1) gn = N - 1;
            u16x8 v = *(const u16x8*)&Bh[(size_t)gn * K + k0 + s * 8];
            *(u16x8*)&Bs[r * 40 + s * 8] = v;
            if constexpr (SPLIT) {
                u16x8 vl = *(const u16x8*)&Bl[(size_t)gn * K + k0 + s * 8];
                *(u16x8*)&Blo[r * 40 + s * 8] = vl;
            }
        }
        __syncthreads();

        s16x8 af[4], bf[4];
        #pragma unroll
        for (int mt = 0; mt < 4; ++mt)
            af[mt] = *(const s16x8*)&Ah[(wm + mt * 16 + l15) * 40 + quad * 8];
        #pragma unroll
        for (int nt = 0; nt < 4; ++nt)
            bf[nt] = *(const s16x8*)&Bs[(wn + nt * 16 + l15) * 40 + quad * 8];

        if constexpr (SPLIT) {
            s16x8 alf[4], blf[4];
            #pragma unroll
            for (int mt = 0; mt < 4; ++mt)
                alf[mt] = *(const s16x8*)&Al[(wm + mt * 16 + l15) * 40 + quad * 8];
            #pragma unroll
            for (int nt = 0; nt < 4; ++nt)
                blf[nt] = *(const s16x8*)&Blo[(wn + nt * 16 + l15) * 40 + quad * 8];
            #pragma unroll
            for (int mt = 0; mt < 4; ++mt)
                #pragma unroll
                for (int nt = 0; nt < 4; ++nt) {
                    acc[mt][nt] = __builtin_amdgcn_mfma_f32_16x16x32_bf16(af[mt], bf[nt], acc[mt][nt], 0, 0, 0);
                    acc[mt][nt] = __builtin_amdgcn_mfma_f32_16x16x32_bf16(af[mt], blf[nt], acc[mt][nt], 0, 0, 0);
                    acc[mt][nt] = __builtin_amdgcn_mfma_f32_16x16x32_bf16(alf[mt], bf[nt], acc[mt][nt], 0, 0, 0);
                }
        } else {
            #pragma unroll
            for (int mt = 0; mt < 4; ++mt)
                #pragma unroll
                for (int nt = 0; nt < 4; ++nt)
                    acc[mt][nt] = __builtin_amdgcn_mfma_f32_16x16x32_bf16(af[mt], bf[nt], acc[mt][nt], 0, 0, 0);
        }
        __syncthreads();
    }

    // ---- epilogue: bias + store ----
    #pragma unroll
    for (int nt = 0; nt < 4; ++nt) {
        int col = bn + wn + nt * 16 + l15;
        float bv = (col < N) ? bias[col] : 0.f;
        #pragma unroll
        for (int mt = 0; mt < 4; ++mt) {
            int row0 = bm + wm + mt * 16 + quad * 4;
            #pragma unroll
            for (int r = 0; r < 4; ++r) {
                int row = row0 + r;
                if (row < M && col < N)
                    C[(size_t)row * N + col] = acc[mt][nt][r] + bv;
            }
        }
    }
}

// ---------------------------------------------------------------------------
// Sampler: 4 queries per block, branchless float4 gather, bf16 output.
__global__ __launch_bounds__(256) void sample_v2(
    const float* __restrict__ val,      // [B][STOT][256] fp32
    const float* __restrict__ raw,      // [MQ][288] fp32 (off 0..191, attn 192..287)
    const float* __restrict__ refp,     // [MQ][2]
    unsigned short* __restrict__ out_bf)// [MQ][256] bf16
{
    const int bq0 = blockIdx.x * 4;
    const int b = bq0 / NQ;
    const int t = threadIdx.x;

    __shared__ float s_aw[4][96];
    __shared__ int   s_idx[4][96][4];
    __shared__ float s_w[4][96][4];

    for (int i = t; i < 384; i += 256) {
        int q = i / 96, p = i - q * 96;
        s_aw[q][p] = raw[(size_t)(bq0 + q) * 288 + 192 + p];
    }
    __syncthreads();

    if (t < 32) {
        int q = t >> 3, h = t & 7;
        float* a = &s_aw[q][h * 12];
        float m = a[0];
        #pragma unroll
        for (int j = 1; j < 12; ++j) m = fmaxf(m, a[j]);
        float e[12], s = 0.f;
        #pragma unroll
        for (int j = 0; j < 12; ++j) { e[j] = expf(a[j] - m); s += e[j]; }
        float inv = 1.f / s;
        #pragma unroll
        for (int j = 0; j < 12; ++j) a[j] = e[j] * inv;
    }
    __syncthreads();

    for (int i = t; i < 384; i += 256) {
        int q = i / 96, p = i - q * 96;
        int h = p / 12, lp = p - h * 12, l = lp >> 2;
        const int dims[3]  = {80, 40, 20};
        const int bases_[3] = {0, 6400, 8000};
        int Wl = dims[l], base = bases_[l];
        size_t ro = (size_t)(bq0 + q) * 288 + h * 24 + lp * 2;
        float rawx = raw[ro], rawy = raw[ro + 1];
        float rx = refp[(size_t)(bq0 + q) * 2];
        float ry = refp[(size_t)(bq0 + q) * 2 + 1];
        float ix = (rx + tanhf(rawx) * 0.5f) * Wl - 0.5f;
        float iy = (ry + tanhf(rawy) * 0.5f) * Wl - 0.5f;
        float x0f = floorf(ix), y0f = floorf(iy);
        float fx = ix - x0f, fy = iy - y0f;
        int x0 = (int)x0f, y0 = (int)y0f;
        float aw = s_aw[q][p];
        float w00 = (1.f - fx) * (1.f - fy) * aw;
        float w01 = fx * (1.f - fy) * aw;
        float w10 = (1.f - fx) * fy * aw;
        float w11 = fx * fy * aw;
        bool vx0 = (unsigned)x0 < (unsigned)Wl;
        bool vx1 = (unsigned)(x0 + 1) < (unsigned)Wl;
        bool vy0 = (unsigned)y0 < (unsigned)Wl;
        bool vy1 = (unsigned)(y0 + 1) < (unsigned)Wl;
        int row0 = base + y0 * Wl, row1 = row0 + Wl;
        s_idx[q][p][0] = (vx0 && vy0) ? row0 + x0     : 0;  s_w[q][p][0] = (vx0 && vy0) ? w00 : 0.f;
        s_idx[q][p][1] = (vx1 && vy0) ? row0 + x0 + 1 : 0;  s_w[q][p][1] = (vx1 && vy0) ? w01 : 0.f;
        s_idx[q][p][2] = (vx0 && vy1) ? row1 + x0     : 0;  s_w[q][p][2] = (vx0 && vy1) ? w10 : 0.f;
        s_idx[q][p][3] = (vx1 && vy1) ? row1 + x0 + 1 : 0;  s_w[q][p][3] = (vx1 && vy1) ? w11 : 0.f;
    }
    __syncthreads();

    const int q = t >> 6, r = t & 63;
    const int h = r >> 3, c4 = r & 7;
    const float4* v4 = (const float4*)val + (size_t)b * STOT * 64 + h * 8 + c4;
    float4 a0 = {0,0,0,0}, a1 = {0,0,0,0}, a2 = {0,0,0,0}, a3 = {0,0,0,0};
    const int*   ip = &s_idx[q][h * 12][0];
    const float* wp = &s_w[q][h * 12][0];
    #pragma unroll
    for (int j = 0; j < 12; ++j) {
        int i0 = ip[j*4+0], i1 = ip[j*4+1], i2 = ip[j*4+2], i3 = ip[j*4+3];
        float w0 = wp[j*4+0], w1 = wp[j*4+1], w2 = wp[j*4+2], w3 = wp[j*4+3];
        float4 v0 = v4[(size_t)i0 * 64];
        float4 v1 = v4[(size_t)i1 * 64];
        float4 v2 = v4[(size_t)i2 * 64];
        float4 v3 = v4[(size_t)i3 * 64];
        a0.x = fmaf(w0, v0.x, a0.x); a0.y = fmaf(w0, v0.y, a0.y);
        a0.z = fmaf(w0, v0.z, a0.z); a0.w = fmaf(w0, v0.w, a0.w);
        a1.x = fmaf(w1, v1.x, a1.x); a1.y = fmaf(w1, v1.y, a1.y);
        a1.z = fmaf(w1, v1.z, a1.z); a1.w = fmaf(w1, v1.w, a1.w);
        a2.x = fmaf(w2, v2.x, a2.x); a2.y = fmaf(w2, v2.y, a2.y);
        a2.z = fmaf(w2, v2.z, a2.z); a2.w = fmaf(w2, v2.w, a2.w);
        a3.x = fmaf(w3, v3.x, a3.x); a3.y = fmaf(w3, v3.y, a3.y);
        a3.z = fmaf(w3, v3.z, a3.z); a3.w = fmaf(w3, v3.w, a3.w);
    }
    float sx = (a0.x + a1.x) + (a2.x + a3.x);
    float sy = (a0.y + a1.y) + (a2.y + a3.y);
    float sz = (a0.z + a1.z) + (a2.z + a3.z);
    float sw = (a0.w + a1.w) + (a2.w + a3.w);
    size_t o = (size_t)(bq0 + q) * 256 + h * 32 + c4 * 4;
    ushort4 ob;
    ob.x = f2bf(sx); ob.y = f2bf(sy); ob.z = f2bf(sz); ob.w = f2bf(sw);
    *(ushort4*)&out_bf[o] = ob;
}

// ---------------------------------------------------------------------------
extern "C" void kernel_launch(void* const* d_in, const int* in_sizes, int n_in,
                              void* d_out, int out_size, void* d_ws, size_t ws_size,
                              hipStream_t stream)
{
    const float* query  = (const float*)d_in[0];
    const float* feat0  = (const float*)d_in[1];
    const float* feat1  = (const float*)d_in[2];
    const float* feat2  = (const float*)d_in[3];
    const float* refp   = (const float*)d_in[4];
    const float* W_off  = (const float*)d_in[5];
    const float* b_off  = (const float*)d_in[6];
    const float* W_attn = (const float*)d_in[7];
    const float* b_attn = (const float*)d_in[8];
    const float* W_val  = (const float*)d_in[9];
    const float* b_val  = (const float*)d_in[10];
    const float* W_out  = (const float*)d_in[11];
    const float* b_out  = (const float*)d_in[12];
    float* out = (float*)d_out;

    // workspace layout
    float*          val  = (float*)d_ws;                       // 33600*256 f32
    float*          raw  = val + (size_t)MQ * 256;             // 33600*288 f32
    unsigned short* Abf  = (unsigned short*)(raw + (size_t)MQ * 288); // 33600*256 bf16
    unsigned short* outb = Abf;                                // reuse (Abf dead after val GEMM)
    unsigned short* Wvt  = Abf + (size_t)MQ * 256;             // 256*256
    unsigned short* Wot  = Wvt + 256 * 256;
    unsigned short* Wch  = Wot + 256 * 256;                    // 288*256
    unsigned short* Wcl  = Wch + 288 * 256;
    float*          bcat = (float*)(Wcl + 288 * 256);          // 288 f32

    dim3 blk(256);

    // weight / feat prep
    tp_w<<<dim3(8, 8), blk, 0, stream>>>(W_val, 256, Wvt, nullptr, 0);
    tp_w<<<dim3(8, 8), blk, 0, stream>>>(W_out, 256, Wot, nullptr, 0);
    tp_w<<<dim3(6, 8), blk, 0, stream>>>(W_off, 192, Wch, Wcl, 0);
    tp_w<<<dim3(3, 8), blk, 0, stream>>>(W_attn, 96, Wch, Wcl, 192);
    cat_bias<<<dim3(2), blk, 0, stream>>>(b_off, b_attn, bcat);
    tp_feat<<<dim3(200, 8, BATCH), blk, 0, stream>>>(feat0, 6400, 0, Abf);
    tp_feat<<<dim3(50, 8, BATCH), blk, 0, stream>>>(feat1, 1600, 6400, Abf);
    tp_feat<<<dim3(13, 8, BATCH), blk, 0, stream>>>(feat2, 400, 8000, Abf);

    // value projection (plain bf16 MFMA)
    gemm_bt<false><<<dim3(2, 263), blk, 0, stream>>>(Abf, Wvt, nullptr, b_val, val, MQ, 256, 256);
    // offsets + attn logits, fused N=288 (bf16x2 split for accuracy)
    gemm_bt<true><<<dim3(3, 263), blk, 0, stream>>>(query, Wch, Wcl, bcat, raw, MQ, 288, 256);
    // deformable sampling
    sample_v2<<<dim3(MQ / 4), blk, 0, stream>>>(val, raw, refp, outb);
    // output projection
    gemm_bt<false><<<dim3(2, 263), blk, 0, stream>>>(outb, Wot, nullptr, b_out, out, MQ, 256, 256);
}

// Round 3
// 281.006 us; speedup vs baseline: 2.9670x; 1.1306x over previous
//
#include <hip/hip_runtime.h>
#include <math.h>

#define NH    8
#define NPT   4
#define DIM   256
#define NQ    8400
#define BATCH 4
#define STOT  8400
#define MQ    (BATCH * NQ)   // 33600

typedef __attribute__((ext_vector_type(8))) short  s16x8;
typedef __attribute__((ext_vector_type(8))) unsigned short u16x8;
typedef __attribute__((ext_vector_type(4))) float  f32x4;

static __device__ __forceinline__ unsigned short f2bf(float x) {
    union { float f; unsigned u; } v; v.f = x;
    unsigned r = v.u + 0x7fffu + ((v.u >> 16) & 1u);   // RNE
    return (unsigned short)(r >> 16);
}
static __device__ __forceinline__ float bf2f(unsigned short h) {
    union { float f; unsigned u; } v; v.u = ((unsigned)h) << 16;
    return v.f;
}

// ---------------------------------------------------------------------------
// Transpose-convert W[K][Nw] fp32 -> outH[(n0+n)*256 + k] bf16 (+ lo plane).
__global__ __launch_bounds__(256) void tp_w(
    const float* __restrict__ W, int Nw,
    unsigned short* __restrict__ outH, unsigned short* __restrict__ outL, int n0)
{
    __shared__ float tile[32][33];
    const int t = threadIdx.x;
    const int nb = blockIdx.x * 32, k0 = blockIdx.y * 32;
    const int c = t & 31, r = t >> 5;
    #pragma unroll
    for (int i = 0; i < 4; ++i) {
        int k = k0 + r + i * 8, n = nb + c;
        tile[r + i * 8][c] = (n < Nw) ? W[(size_t)k * Nw + n] : 0.f;
    }
    __syncthreads();
    #pragma unroll
    for (int i = 0; i < 4; ++i) {
        int n = nb + r + i * 8, k = k0 + c;
        if (n < Nw) {
            float x = tile[c][r + i * 8];
            unsigned short h = f2bf(x);
            outH[(size_t)(n0 + n) * 256 + k] = h;
            if (outL) outL[(size_t)(n0 + n) * 256 + k] = f2bf(x - bf2f(h));
        }
    }
}

// feat [B][256][S] fp32 -> Abf[(b*STOT + base + s)*256 + k] bf16
__global__ __launch_bounds__(256) void tp_feat(
    const float* __restrict__ feat, int S, int base,
    unsigned short* __restrict__ Abf)
{
    __shared__ float tile[32][33];
    const int t = threadIdx.x;
    const int s0 = blockIdx.x * 32, k0 = blockIdx.y * 32, b = blockIdx.z;
    const int c = t & 31, r = t >> 5;
    #pragma unroll
    for (int i = 0; i < 4; ++i) {
        int k = k0 + r + i * 8, s = s0 + c;
        tile[r + i * 8][c] = (s < S) ? feat[((size_t)b * 256 + k) * S + s] : 0.f;
    }
    __syncthreads();
    #pragma unroll
    for (int i = 0; i < 4; ++i) {
        int s = s0 + r + i * 8, k = k0 + c;
        if (s < S)
            Abf[((size_t)(b * STOT + base + s)) * 256 + k] = f2bf(tile[c][r + i * 8]);
    }
}

__global__ void cat_bias(const float* __restrict__ boff, const float* __restrict__ battn,
                         float* __restrict__ bcat)
{
    int t = blockIdx.x * 256 + threadIdx.x;
    if (t < 192) bcat[t] = boff[t];
    else if (t < 288) bcat[t] = battn[t - 192];
}

// ---------------------------------------------------------------------------
// C = A * B^T + bias.  SPLIT: A fp32 -> hi/lo bf16x2, 3 MFMA passes.
// MODE 0: C fp32 [M][N].  MODE 1: bf16 head-plane out [(b*8+h)*STOT + s][32].
template<bool SPLIT, int MODE>
__global__ __launch_bounds__(256) void gemm_bt(
    const void* __restrict__ Aptr,
    const unsigned short* __restrict__ Bh, const unsigned short* __restrict__ Bl,
    const float* __restrict__ bias, void* __restrict__ Cptr,
    int M, int N, int K)
{
    __shared__ unsigned short Ah[128 * 40];
    __shared__ unsigned short Bs[128 * 40];
    __shared__ unsigned short Al[SPLIT ? 128 * 40 : 8];
    __shared__ unsigned short Blo[SPLIT ? 128 * 40 : 8];

    const int t = threadIdx.x;
    const int bn = blockIdx.x * 128, bm = blockIdx.y * 128;
    const int lane = t & 63, w = t >> 6;
    const int wm = (w & 1) * 64, wn = (w >> 1) * 64;
    const int l15 = lane & 15, quad = lane >> 4;

    f32x4 acc[4][4];
    #pragma unroll
    for (int i = 0; i < 4; ++i)
        #pragma unroll
        for (int j = 0; j < 4; ++j)
            acc[i][j] = (f32x4){0.f, 0.f, 0.f, 0.f};

    for (int k0 = 0; k0 < K; k0 += 32) {
        #pragma unroll
        for (int cc = 0; cc < 2; ++cc) {
            int cid = t + cc * 256;
            int r = cid >> 2, s = cid & 3;
            int gr = bm + r; if (gr > M - 1) gr = M - 1;
            if constexpr (SPLIT) {
                const float* ap = (const float*)Aptr + (size_t)gr * K + k0 + s * 8;
                float4 f0 = *(const float4*)ap;
                float4 f1 = *(const float4*)(ap + 4);
                float xs[8] = {f0.x, f0.y, f0.z, f0.w, f1.x, f1.y, f1.z, f1.w};
                u16x8 hv, lv;
                #pragma unroll
                for (int e = 0; e < 8; ++e) {
                    unsigned short h = f2bf(xs[e]);
                    hv[e] = h;
                    lv[e] = f2bf(xs[e] - bf2f(h));
                }
                *(u16x8*)&Ah[r * 40 + s * 8] = hv;
                *(u16x8*)&Al[r * 40 + s * 8] = lv;
            } else {
                u16x8 v = *(const u16x8*)((const unsigned short*)Aptr + (size_t)gr * K + k0 + s * 8);
                *(u16x8*)&Ah[r * 40 + s * 8] = v;
            }
        }
        #pragma unroll
        for (int cc = 0; cc < 2; ++cc) {
            int cid = t + cc * 256;
            int r = cid >> 2, s = cid & 3;
            int gn = bn + r; if (gn > N - 1) gn = N - 1;
            u16x8 v = *(const u16x8*)&Bh[(size_t)gn * K + k0 + s * 8];
            *(u16x8*)&Bs[r * 40 + s * 8] = v;
            if constexpr (SPLIT) {
                u16x8 vl = *(const u16x8*)&Bl[(size_t)gn * K + k0 + s * 8];
                *(u16x8*)&Blo[r * 40 + s * 8] = vl;
            }
        }
        __syncthreads();

        s16x8 af[4], bf[4];
        #pragma unroll
        for (int mt = 0; mt < 4; ++mt)
            af[mt] = *(const s16x8*)&Ah[(wm + mt * 16 + l15) * 40 + quad * 8];
        #pragma unroll
        for (int nt = 0; nt < 4; ++nt)
            bf[nt] = *(const s16x8*)&Bs[(wn + nt * 16 + l15) * 40 + quad * 8];

        if constexpr (SPLIT) {
            s16x8 alf[4], blf[4];
            #pragma unroll
            for (int mt = 0; mt < 4; ++mt)
                alf[mt] = *(const s16x8*)&Al[(wm + mt * 16 + l15) * 40 + quad * 8];
            #pragma unroll
            for (int nt = 0; nt < 4; ++nt)
                blf[nt] = *(const s16x8*)&Blo[(wn + nt * 16 + l15) * 40 + quad * 8];
            #pragma unroll
            for (int mt = 0; mt < 4; ++mt)
                #pragma unroll
                for (int nt = 0; nt < 4; ++nt) {
                    acc[mt][nt] = __builtin_amdgcn_mfma_f32_16x16x32_bf16(af[mt], bf[nt], acc[mt][nt], 0, 0, 0);
                    acc[mt][nt] = __builtin_amdgcn_mfma_f32_16x16x32_bf16(af[mt], blf[nt], acc[mt][nt], 0, 0, 0);
                    acc[mt][nt] = __builtin_amdgcn_mfma_f32_16x16x32_bf16(alf[mt], bf[nt], acc[mt][nt], 0, 0, 0);
                }
        } else {
            #pragma unroll
            for (int mt = 0; mt < 4; ++mt)
                #pragma unroll
                for (int nt = 0; nt < 4; ++nt)
                    acc[mt][nt] = __builtin_amdgcn_mfma_f32_16x16x32_bf16(af[mt], bf[nt], acc[mt][nt], 0, 0, 0);
        }
        __syncthreads();
    }

    #pragma unroll
    for (int nt = 0; nt < 4; ++nt) {
        int col = bn + wn + nt * 16 + l15;
        float bv = (col < N) ? bias[col] : 0.f;
        #pragma unroll
        for (int mt = 0; mt < 4; ++mt) {
            int row0 = bm + wm + mt * 16 + quad * 4;
            #pragma unroll
            for (int r = 0; r < 4; ++r) {
                int row = row0 + r;
                if (row < M && col < N) {
                    float v = acc[mt][nt][r] + bv;
                    if constexpr (MODE == 0) {
                        ((float*)Cptr)[(size_t)row * N + col] = v;
                    } else {
                        int bb = row / STOT, s = row - bb * STOT;
                        int h = col >> 5, c = col & 31;
                        ((unsigned short*)Cptr)[(((size_t)(bb * 8 + h)) * STOT + s) * 32 + c] = f2bf(v);
                    }
                }
            }
        }
    }
}

// ---------------------------------------------------------------------------
// Sampler v3: 8 queries/block, bf16 head-plane val, 12-load register batches.
__global__ __launch_bounds__(256) void sample_v3(
    const unsigned short* __restrict__ valb, // [B*8][STOT][32] bf16
    const float* __restrict__ raw,           // [MQ][288] (off 0..191, attn 192..287)
    const float* __restrict__ refp,          // [MQ][2]
    unsigned short* __restrict__ out_bf)     // [MQ][256] bf16
{
    const int bq0 = blockIdx.x * 8;
    const int b = bq0 / NQ;          // 8400 % 8 == 0: no straddle
    const int t = threadIdx.x;

    __shared__ int   s_idx[8][96][4];
    __shared__ float s_w[8][96][4];
    __shared__ float s_m[8][8];
    __shared__ float s_inv[8][8];

    // phase 1: per-(q,h) softmax stats
    if (t < 64) {
        int q = t >> 3, h = t & 7;
        const float* a = &raw[(size_t)(bq0 + q) * 288 + 192 + h * 12];
        float m = a[0];
        #pragma unroll
        for (int j = 1; j < 12; ++j) m = fmaxf(m, a[j]);
        float s = 0.f;
        #pragma unroll
        for (int j = 0; j < 12; ++j) s += expf(a[j] - m);
        s_m[q][h] = m;
        s_inv[q][h] = 1.f / s;
    }
    __syncthreads();

    // phase 2: per-(q,point) idx/weight setup
    for (int i = t; i < 768; i += 256) {
        int q = i / 96, p = i - q * 96;
        int h = p / 12, lp = p - h * 12, l = lp >> 2;
        const int dims[3]   = {80, 40, 20};
        const int bases_[3] = {0, 6400, 8000};
        int Wl = dims[l], base = bases_[l];
        size_t ro = (size_t)(bq0 + q) * 288;
        float logit = raw[ro + 192 + p];
        float aw = expf(logit - s_m[q][h]) * s_inv[q][h];
        float rawx = raw[ro + h * 24 + lp * 2 + 0];
        float rawy = raw[ro + h * 24 + lp * 2 + 1];
        float rx = refp[(size_t)(bq0 + q) * 2];
        float ry = refp[(size_t)(bq0 + q) * 2 + 1];
        float ix = (rx + tanhf(rawx) * 0.5f) * Wl - 0.5f;
        float iy = (ry + tanhf(rawy) * 0.5f) * Wl - 0.5f;
        float x0f = floorf(ix), y0f = floorf(iy);
        float fx = ix - x0f, fy = iy - y0f;
        int x0 = (int)x0f, y0 = (int)y0f;
        float w00 = (1.f - fx) * (1.f - fy) * aw;
        float w01 = fx * (1.f - fy) * aw;
        float w10 = (1.f - fx) * fy * aw;
        float w11 = fx * fy * aw;
        bool vx0 = (unsigned)x0 < (unsigned)Wl;
        bool vx1 = (unsigned)(x0 + 1) < (unsigned)Wl;
        bool vy0 = (unsigned)y0 < (unsigned)Wl;
        bool vy1 = (unsigned)(y0 + 1) < (unsigned)Wl;
        int row0 = base + y0 * Wl, row1 = row0 + Wl;
        s_idx[q][p][0] = (vx0 && vy0) ? row0 + x0     : 0;  s_w[q][p][0] = (vx0 && vy0) ? w00 : 0.f;
        s_idx[q][p][1] = (vx1 && vy0) ? row0 + x0 + 1 : 0;  s_w[q][p][1] = (vx1 && vy0) ? w01 : 0.f;
        s_idx[q][p][2] = (vx0 && vy1) ? row1 + x0     : 0;  s_w[q][p][2] = (vx0 && vy1) ? w10 : 0.f;
        s_idx[q][p][3] = (vx1 && vy1) ? row1 + x0 + 1 : 0;  s_w[q][p][3] = (vx1 && vy1) ? w11 : 0.f;
    }
    __syncthreads();

    // phase 3: gather. 4 lanes per (q,h); 12-load register batches.
    const int q = t >> 5;
    const int h = (t >> 2) & 7;
    const int l4 = t & 3;
    const unsigned short* vb = valb + ((size_t)(b * 8 + h) * STOT) * 32 + l4 * 8;
    const int*   ip = &s_idx[q][h * 12][0];
    const float* wp = &s_w[q][h * 12][0];
    float acc[8] = {};
    #pragma unroll
    for (int pp = 0; pp < 4; ++pp) {
        int   ix[12]; float ww[12]; u16x8 v[12];
        #pragma unroll
        for (int k = 0; k < 12; ++k) { ix[k] = ip[pp * 12 + k]; ww[k] = wp[pp * 12 + k]; }
        #pragma unroll
        for (int k = 0; k < 12; ++k) v[k] = *(const u16x8*)(vb + (size_t)ix[k] * 32);
        #pragma unroll
        for (int k = 0; k < 12; ++k)
            #pragma unroll
            for (int c = 0; c < 8; ++c)
                acc[c] = fmaf(ww[k], bf2f(v[k][c]), acc[c]);
    }

    u16x8 ob;
    #pragma unroll
    for (int c = 0; c < 8; ++c) ob[c] = f2bf(acc[c]);
    *(u16x8*)&out_bf[(size_t)(bq0 + q) * 256 + h * 32 + l4 * 8] = ob;
}

// ---------------------------------------------------------------------------
extern "C" void kernel_launch(void* const* d_in, const int* in_sizes, int n_in,
                              void* d_out, int out_size, void* d_ws, size_t ws_size,
                              hipStream_t stream)
{
    const float* query  = (const float*)d_in[0];
    const float* feat0  = (const float*)d_in[1];
    const float* feat1  = (const float*)d_in[2];
    const float* feat2  = (const float*)d_in[3];
    const float* refp   = (const float*)d_in[4];
    const float* W_off  = (const float*)d_in[5];
    const float* b_off  = (const float*)d_in[6];
    const float* W_attn = (const float*)d_in[7];
    const float* b_attn = (const float*)d_in[8];
    const float* W_val  = (const float*)d_in[9];
    const float* b_val  = (const float*)d_in[10];
    const float* W_out  = (const float*)d_in[11];
    const float* b_out  = (const float*)d_in[12];
    float* out = (float*)d_out;

    // workspace layout (~74 MB)
    unsigned short* valb = (unsigned short*)d_ws;              // MQ*256 bf16
    float*          raw  = (float*)(valb + (size_t)MQ * 256);  // MQ*288 f32
    unsigned short* Abf  = (unsigned short*)(raw + (size_t)MQ * 288); // MQ*256 bf16
    unsigned short* outb = Abf;                                // reuse after val GEMM
    unsigned short* Wvt  = Abf + (size_t)MQ * 256;
    unsigned short* Wot  = Wvt + 256 * 256;
    unsigned short* Wch  = Wot + 256 * 256;                    // 288*256
    unsigned short* Wcl  = Wch + 288 * 256;
    float*          bcat = (float*)(Wcl + 288 * 256);

    dim3 blk(256);

    tp_w<<<dim3(8, 8), blk, 0, stream>>>(W_val, 256, Wvt, nullptr, 0);
    tp_w<<<dim3(8, 8), blk, 0, stream>>>(W_out, 256, Wot, nullptr, 0);
    tp_w<<<dim3(6, 8), blk, 0, stream>>>(W_off, 192, Wch, Wcl, 0);
    tp_w<<<dim3(3, 8), blk, 0, stream>>>(W_attn, 96, Wch, Wcl, 192);
    cat_bias<<<dim3(2), blk, 0, stream>>>(b_off, b_attn, bcat);
    tp_feat<<<dim3(200, 8, BATCH), blk, 0, stream>>>(feat0, 6400, 0, Abf);
    tp_feat<<<dim3(50, 8, BATCH), blk, 0, stream>>>(feat1, 1600, 6400, Abf);
    tp_feat<<<dim3(13, 8, BATCH), blk, 0, stream>>>(feat2, 400, 8000, Abf);

    // value projection -> bf16 head planes
    gemm_bt<false, 1><<<dim3(2, 263), blk, 0, stream>>>(Abf, Wvt, nullptr, b_val, valb, MQ, 256, 256);
    // offsets + attn logits (bf16x2 split)
    gemm_bt<true, 0><<<dim3(3, 263), blk, 0, stream>>>(query, Wch, Wcl, bcat, raw, MQ, 288, 256);
    // deformable sampling
    sample_v3<<<dim3(MQ / 8), blk, 0, stream>>>(valb, raw, refp, outb);
    // output projection
    gemm_bt<false, 0><<<dim3(2, 263), blk, 0, stream>>>(outb, Wot, nullptr, b_out, out, MQ, 256, 256);
}